// Round 8
// baseline (224.128 us; speedup 1.0000x reference)
//
#include <hip/hip_runtime.h>
#include <hip/hip_bf16.h>
#include <cmath>

#define S_LEN 2048
#define D_DIM 64
#define BM 128           // rows per block (two 64-row mask blocks)
#define BN 64            // K-tile cols (== mask BLOCK_SIZE)
#define NKT 32
#define NBH 32
#define NRT (S_LEN / BM) // 16 row-tiles per head
#define PSTR 72          // P bf16 row stride (144B, 16B-aligned for b128)
#define LDP 72           // fallback kernel stride

typedef float f32x4 __attribute__((ext_vector_type(4)));
typedef short s16x8 __attribute__((ext_vector_type(8)));
typedef unsigned int u32x2 __attribute__((ext_vector_type(2)));

__device__ __forceinline__ unsigned short f2b(float x) {
  union { float f; unsigned int u; } un; un.f = x;
  unsigned int u = un.u;
  unsigned int r = (u + 0x7FFF + ((u >> 16) & 1)) >> 16;  // RNE
  return (unsigned short)r;
}

__device__ __forceinline__ unsigned int fbits(float x) {
  union { float f; unsigned int u; } un; un.f = x; return un.u;
}

// pack two fp32 -> (bf16(lo) | bf16(hi)<<16), truncating, one v_perm_b32
__device__ __forceinline__ unsigned int pk2(float lo, float hi) {
  return __builtin_amdgcn_perm(fbits(hi), fbits(lo), 0x07060302u);
}

__device__ __forceinline__ s16x8 pack8(float4 a, float4 b) {
  s16x8 r;
  r[0] = (short)f2b(a.x); r[1] = (short)f2b(a.y);
  r[2] = (short)f2b(a.z); r[3] = (short)f2b(a.w);
  r[4] = (short)f2b(b.x); r[5] = (short)f2b(b.y);
  r[6] = (short)f2b(b.z); r[7] = (short)f2b(b.w);
  return r;
}

// async global->LDS, 16B per lane (dest linear: wave-uniform base + lane*16)
typedef __attribute__((address_space(1))) const unsigned int GU32;
typedef __attribute__((address_space(3))) unsigned int LU32;
__device__ __forceinline__ void gload16(const void* g, void* l) {
  __builtin_amdgcn_global_load_lds((GU32*)g, (LU32*)l, 16, 0, 0);
}

// ---- prep: K fp32->bf16 pack + V fp32->bf16 transpose, one kernel ----
__global__ __launch_bounds__(256) void prep_kernel(
    const float* __restrict__ K, const float* __restrict__ V,
    unsigned short* __restrict__ Kb, unsigned short* __restrict__ Vt) {
  __shared__ unsigned short L[64 * 72];
  const int tid = threadIdx.x;
  const int bh = blockIdx.y;
  const int s0 = blockIdx.x * 64;

  const float* Kp = K + ((size_t)bh * S_LEN + s0) * D_DIM;
  unsigned short* Ko = Kb + ((size_t)bh * S_LEN + s0) * D_DIM;
#pragma unroll
  for (int it = 0; it < 2; ++it) {
    int off = tid * 8 + it * 2048;
    float4 a = *(const float4*)(Kp + off);
    float4 b = *(const float4*)(Kp + off + 4);
    *(s16x8*)(Ko + off) = pack8(a, b);
  }

  const float* Vp = V + ((size_t)bh * S_LEN + s0) * D_DIM;
  for (int it = 0; it < 4; ++it) {
    int lin = it * 256 + tid;
    int r = lin >> 4;
    int c = (lin & 15) << 2;
    float4 v = *(const float4*)(Vp + (size_t)r * D_DIM + c);
    L[(c + 0) * 72 + r] = f2b(v.x);
    L[(c + 1) * 72 + r] = f2b(v.y);
    L[(c + 2) * 72 + r] = f2b(v.z);
    L[(c + 3) * 72 + r] = f2b(v.w);
  }
  __syncthreads();
  unsigned short* Vo = Vt + (size_t)bh * D_DIM * S_LEN + s0;
  for (int it = 0; it < 2; ++it) {
    int lin = it * 256 + tid;
    int d = lin >> 3;
    int c8 = (lin & 7) * 8;
    s16x8 v = *(const s16x8*)&L[d * 72 + c8];
    *(s16x8*)(Vo + (size_t)d * S_LEN + c8) = v;
  }
}

// ---- main fused kernel: swapped QK (lane-local q-rows), bf16 P, reg stores ----
__global__ __launch_bounds__(512, 4) void bsattn_fast(
    const float* __restrict__ Qg_, const unsigned short* __restrict__ Kb,
    const unsigned short* __restrict__ Vtb, float* __restrict__ outg,
    float* __restrict__ attng, float* __restrict__ Mg) {
  // Stage: pass 1 = 4-deep K ring; pass 2 = [0,1] K dbuf, [2,3] V dbuf.
  // Linear [64 rows][64 bf16], source-pre-swizzled 16B cols: (row, c^(row&7)).
  __shared__ __align__(16) unsigned short Stage[4][64 * 64];   // 32 KB
  __shared__ __align__(16) unsigned short Pb[BM * PSTR];       // 18 KB bf16 P

  const int tid = threadIdx.x;
  const int w  = tid >> 6;      // 0..7
  const int l  = tid & 63;
  const int lr = l & 15;
  const int lh = l >> 4;

  // XCD swizzle: all 16 row-tiles of a head on one XCD
  const int lin = blockIdx.x;
  const int xcd = lin & 7;
  const int ix  = lin >> 3;
  const int bh  = xcd + 8 * (ix >> 4);
  const int rt  = ix & 15;
  const int row0 = rt * BM;
  const int mb  = rt * 2 + (w >> 2);   // this wave's own (masked) mask-block

  const unsigned short* Kh = Kb  + (size_t)bh * S_LEN * D_DIM;
  const unsigned short* Vh = Vtb + (size_t)bh * D_DIM * S_LEN;
  float* outp  = outg  + (size_t)bh * S_LEN * D_DIM;
  float* attnp = attng + (size_t)bh * S_LEN * S_LEN;

  const float* Qrow = Qg_ + ((size_t)bh * S_LEN + row0 + w * 16 + lr) * D_DIM;
  const s16x8 qf0 = pack8(*(const float4*)(Qrow + lh * 8),
                          *(const float4*)(Qrow + lh * 8 + 4));
  const s16x8 qf1 = pack8(*(const float4*)(Qrow + 32 + lh * 8),
                          *(const float4*)(Qrow + 32 + lh * 8 + 4));

  const float C = 0.18033688011112042f;  // log2(e)/8

  auto STAGE_K = [&](int kt, int b) {
    int row = tid >> 3;
    int c = (tid & 7) ^ (row & 7);
    gload16(Kh + (size_t)kt * 4096 + row * 64 + c * 8, &Stage[b][tid * 8]);
  };
  auto STAGE_V = [&](int kt, int b) {
    int row = tid >> 3;
    int c = (tid & 7) ^ (row & 7);
    gload16(Vh + (size_t)row * S_LEN + kt * 64 + c * 8, &Stage[b][tid * 8]);
  };

  // swapped QK^T: acc[j16] = mfma(K-frag, Q-frag) ->
  //   lane (lr,lh): D col = lr = q-row (w*16+lr), D row = lh*4+r = kcol 16j16+4lh+r
  auto QKACC = [&](int b, f32x4* acc) {
#pragma unroll
    for (int j16 = 0; j16 < 4; ++j16) {
      const int j = j16 * 16 + lr;
      const int sw = (j & 7) * 8;
      const s16x8 kf0 = *(const s16x8*)&Stage[b][j * 64 + ((lh * 8) ^ sw)];
      const s16x8 kf1 = *(const s16x8*)&Stage[b][j * 64 + ((32 + lh * 8) ^ sw)];
      f32x4 a = {0.f, 0.f, 0.f, 0.f};
      a = __builtin_amdgcn_mfma_f32_16x16x32_bf16(kf0, qf0, a, 0, 0, 0);
      a = __builtin_amdgcn_mfma_f32_16x16x32_bf16(kf1, qf1, a, 0, 0, 0);
      acc[j16] = a;
    }
  };

  // ======== pass 1: denominators, 4-deep counted-vmcnt ring ========
  float l_run = 0.f;
  STAGE_K(0, 0); STAGE_K(1, 1); STAGE_K(2, 2);
  asm volatile("s_waitcnt vmcnt(2)" ::: "memory");
  __builtin_amdgcn_s_barrier();
  __builtin_amdgcn_sched_barrier(0);

  for (int kt = 0; kt < NKT; ++kt) {
    STAGE_K((kt + 3) & 31, (kt + 3) & 3);   // wraps land on tiles 0..2 = reused by pass 2
    f32x4 acc[4];
    QKACC(kt & 3, acc);
    const float ts = (kt == mb) ? 0.f : 1.f;
    float s = 0.f;
#pragma unroll
    for (int j16 = 0; j16 < 4; ++j16)
#pragma unroll
      for (int r = 0; r < 4; ++r) {
        float e = __builtin_amdgcn_exp2f(acc[j16][r] * C);
        if (j16 == 0 && r == 0 && lh == 0) e = 0.f;  // head col (kcol==0)
        s += e;
      }
    l_run += ts * s;
    __builtin_amdgcn_sched_barrier(0);
    asm volatile("s_waitcnt vmcnt(2)" ::: "memory");
    __builtin_amdgcn_s_barrier();
    __builtin_amdgcn_sched_barrier(0);
  }

  // settle wrap loads (Stage[0..2] hold K tiles 0..2, complete)
  asm volatile("s_waitcnt vmcnt(0)" ::: "memory");

  // denominator reduce across lh groups (lanes lr, lr+16, lr+32, lr+48)
  l_run += __shfl_xor(l_run, 16);
  l_run += __shfl_xor(l_run, 32);
  const float invl = 1.0f / l_run;

  // M mask output folded here (write pipe otherwise idle): 4 rows/block
  {
    const int i0 = blockIdx.x * 4;
#pragma unroll
    for (int rr = 0; rr < 4; ++rr) {
      const int i = i0 + rr;
      const int iblk = i >> 6;
      const int c0 = tid * 4;
      f32x4 v;
#pragma unroll
      for (int c = 0; c < 4; ++c) {
        const int j = c0 + c;
        v[c] = ((j >> 6) == iblk) || ((j & 63) == 0) ? 1.f : 0.f;
      }
      __builtin_nontemporal_store(v, (f32x4*)(Mg + (size_t)i * S_LEN + c0));
    }
  }

  // pass-2 prologue: K0,K1 already staged (wraps); V0 into Stage[2]
  STAGE_V(0, 2);
  __syncthreads();   // drains V0 + M stores; all waves synced

  // ======== pass 2: QK -> attn (reg stores) -> bf16 P -> PV ========
  f32x4 oacc[4];
#pragma unroll
  for (int d16 = 0; d16 < 4; ++d16) oacc[d16] = (f32x4){0.f, 0.f, 0.f, 0.f};

  float* arow_base = attnp + (size_t)(row0 + w * 16 + lr) * S_LEN + lh * 4;
  unsigned short* prow = &Pb[(w * 16 + lr) * PSTR];

  for (int kt = 0; kt < NKT; ++kt) {
    const int kb = kt & 1;
    const int vb = 2 + (kt & 1);
    // loads FIRST (vmcnt(4) at the barrier retires exactly these two)
    if (kt < NKT - 1) { STAGE_K(kt + 1, (kt + 1) & 1); STAGE_V(kt + 1, 2 + ((kt + 1) & 1)); }

    f32x4 acc[4];
    QKACC(kb, acc);
    const float sc = ((kt == mb) ? 0.f : 1.f) * invl;

#pragma unroll
    for (int j16 = 0; j16 < 4; ++j16) {
      float e0 = __builtin_amdgcn_exp2f(acc[j16][0] * C) * sc;
      float e1 = __builtin_amdgcn_exp2f(acc[j16][1] * C) * sc;
      float e2 = __builtin_amdgcn_exp2f(acc[j16][2] * C) * sc;
      float e3 = __builtin_amdgcn_exp2f(acc[j16][3] * C) * sc;
      if (j16 == 0 && lh == 0) e0 = 0.f;   // head col of this tile
      f32x4 ev = {e0, e1, e2, e3};
      // attn store straight from registers: 16 rows x 64B runs, nt
      __builtin_nontemporal_store(ev, (f32x4*)(arow_base + kt * BN + j16 * 16));
      // P -> bf16 LDS (wave-private row), 8B per j16
      u32x2 up = {pk2(e0, e1), pk2(e2, e3)};
      *(u32x2*)(prow + j16 * 16 + lh * 4) = up;
    }

    // PV: A = P row (lane-local q-row), B = V^T fragment
#pragma unroll
    for (int ks = 0; ks < 2; ++ks) {
      const s16x8 pf = *(const s16x8*)(prow + ks * 32 + lh * 8);
#pragma unroll
      for (int d16 = 0; d16 < 4; ++d16) {
        const int vr = d16 * 16 + lr;
        const s16x8 vf = *(const s16x8*)
            &Stage[vb][vr * 64 + ((ks * 32 + lh * 8) ^ ((vr & 7) * 8))];
        oacc[d16] = __builtin_amdgcn_mfma_f32_16x16x32_bf16(pf, vf, oacc[d16], 0, 0, 0);
      }
    }

    // counted vmcnt: retire the 2 stage loads, leave newest nt stores in flight
    __builtin_amdgcn_sched_barrier(0);
    asm volatile("s_waitcnt vmcnt(4)" ::: "memory");
    __builtin_amdgcn_s_barrier();
    __builtin_amdgcn_sched_barrier(0);
  }

#pragma unroll
  for (int d16 = 0; d16 < 4; ++d16)
#pragma unroll
    for (int r = 0; r < 4; ++r) {
      int irow = w * 16 + lh * 4 + r;
      __builtin_nontemporal_store(
          oacc[d16][r], outp + (size_t)(row0 + irow) * D_DIM + d16 * 16 + lr);
    }
}

// ---- fallback (self-contained, fp32 inputs) if ws too small ----
__global__ __launch_bounds__(256) void bsattn_kernel(
    const float* __restrict__ Qg_, const float* __restrict__ Kg_,
    const float* __restrict__ Vg_, float* __restrict__ outg,
    float* __restrict__ attng) {
  __shared__ __align__(16) unsigned short Ql[64 * LDP];
  __shared__ __align__(16) unsigned short Kl[64 * LDP];
  __shared__ __align__(16) unsigned short Vt[64 * LDP];
  __shared__ __align__(16) unsigned short Pp[64 * LDP];
  const int tid = threadIdx.x;
  const int w  = tid >> 6;
  const int l  = tid & 63;
  const int lr = l & 15;
  const int lh = l >> 4;
  const int rt = blockIdx.x;
  const int bh = blockIdx.y;
  const int row0 = rt * 64;
  const float* Qg = Qg_ + (size_t)bh * S_LEN * D_DIM;
  const float* Kg = Kg_ + (size_t)bh * S_LEN * D_DIM;
  const float* Vg = Vg_ + (size_t)bh * S_LEN * D_DIM;
  float* outp  = outg  + (size_t)bh * S_LEN * D_DIM;
  float* attnp = attng + (size_t)bh * S_LEN * S_LEN;
  for (int it = 0; it < 4; ++it) {
    int lin2 = it * 256 + tid;
    int r = lin2 >> 4;
    int c = (lin2 & 15) << 2;
    const float4 v = *(const float4*)(Qg + (size_t)(row0 + r) * D_DIM + c);
    ushort4 bb; bb.x = f2b(v.x); bb.y = f2b(v.y); bb.z = f2b(v.z); bb.w = f2b(v.w);
    *(ushort4*)&Ql[r * LDP + c] = bb;
  }
  __syncthreads();
  const s16x8 qf0 = *(const s16x8*)&Ql[(w * 16 + lr) * LDP + lh * 8];
  const s16x8 qf1 = *(const s16x8*)&Ql[(w * 16 + lr) * LDP + 32 + lh * 8];
  float m_run[4] = {-1e30f, -1e30f, -1e30f, -1e30f};
  float l_run[4] = {0.f, 0.f, 0.f, 0.f};
  for (int kt = 0; kt < NKT; ++kt) {
    if (kt == rt) continue;
    __syncthreads();
    const float* Kt = Kg + (size_t)kt * BN * D_DIM;
    for (int it = 0; it < 4; ++it) {
      int lin2 = it * 256 + tid;
      int r = lin2 >> 4;
      int c = (lin2 & 15) << 2;
      const float4 v = *(const float4*)(Kt + r * D_DIM + c);
      ushort4 bb; bb.x = f2b(v.x); bb.y = f2b(v.y); bb.z = f2b(v.z); bb.w = f2b(v.w);
      *(ushort4*)&Kl[r * LDP + c] = bb;
    }
    __syncthreads();
    f32x4 acc[4];
#pragma unroll
    for (int j16 = 0; j16 < 4; ++j16) {
      f32x4 a = {0.f, 0.f, 0.f, 0.f};
      s16x8 kf0 = *(const s16x8*)&Kl[(j16 * 16 + lr) * LDP + lh * 8];
      a = __builtin_amdgcn_mfma_f32_16x16x32_bf16(qf0, kf0, a, 0, 0, 0);
      s16x8 kf1 = *(const s16x8*)&Kl[(j16 * 16 + lr) * LDP + 32 + lh * 8];
      a = __builtin_amdgcn_mfma_f32_16x16x32_bf16(qf1, kf1, a, 0, 0, 0);
      acc[j16] = a;
    }
#pragma unroll
    for (int r = 0; r < 4; ++r) {
      float s0 = acc[0][r] * 0.125f;
      if (lr == 0) s0 = -INFINITY;
      float s1 = acc[1][r] * 0.125f;
      float s2 = acc[2][r] * 0.125f;
      float s3 = acc[3][r] * 0.125f;
      float tm = fmaxf(fmaxf(s0, s1), fmaxf(s2, s3));
      float mn = fmaxf(m_run[r], tm);
      float scx = __expf(m_run[r] - mn);
      l_run[r] = l_run[r] * scx + __expf(s0 - mn) + __expf(s1 - mn) +
                 __expf(s2 - mn) + __expf(s3 - mn);
      m_run[r] = mn;
    }
  }
#pragma unroll
  for (int off = 8; off >= 1; off >>= 1) {
#pragma unroll
    for (int r = 0; r < 4; ++r) {
      float mo = __shfl_xor(m_run[r], off);
      float lo = __shfl_xor(l_run[r], off);
      float mn = fmaxf(m_run[r], mo);
      l_run[r] = l_run[r] * __expf(m_run[r] - mn) + lo * __expf(mo - mn);
      m_run[r] = mn;
    }
  }
  float invl[4];
#pragma unroll
  for (int r = 0; r < 4; ++r) invl[r] = 1.0f / l_run[r];
  f32x4 oacc[4];
#pragma unroll
  for (int d16 = 0; d16 < 4; ++d16) oacc[d16] = (f32x4){0.f, 0.f, 0.f, 0.f};
  for (int kt = 0; kt < NKT; ++kt) {
    if (kt == rt) {
      for (int it = 0; it < 4; ++it) {
        int lin2 = it * 256 + tid;
        int r = lin2 >> 4;
        int c = (lin2 & 15) << 2;
        float4 z = {0.f, 0.f, 0.f, 0.f};
        *(float4*)(attnp + (size_t)(row0 + r) * S_LEN + kt * BN + c) = z;
      }
      continue;
    }
    __syncthreads();
    const float* Kt  = Kg + (size_t)kt * BN * D_DIM;
    const float* Vtg = Vg + (size_t)kt * BN * D_DIM;
    for (int it = 0; it < 4; ++it) {
      int lin2 = it * 256 + tid;
      int r = lin2 >> 4;
      int c = (lin2 & 15) << 2;
      const float4 v = *(const float4*)(Kt + r * D_DIM + c);
      ushort4 bb; bb.x = f2b(v.x); bb.y = f2b(v.y); bb.z = f2b(v.z); bb.w = f2b(v.w);
      *(ushort4*)&Kl[r * LDP + c] = bb;
      const float4 vv = *(const float4*)(Vtg + r * D_DIM + c);
      Vt[(c + 0) * LDP + r] = f2b(vv.x);
      Vt[(c + 1) * LDP + r] = f2b(vv.y);
      Vt[(c + 2) * LDP + r] = f2b(vv.z);
      Vt[(c + 3) * LDP + r] = f2b(vv.w);
    }
    __syncthreads();
    f32x4 acc[4];
#pragma unroll
    for (int j16 = 0; j16 < 4; ++j16) {
      f32x4 a = {0.f, 0.f, 0.f, 0.f};
      s16x8 kf0 = *(const s16x8*)&Kl[(j16 * 16 + lr) * LDP + lh * 8];
      a = __builtin_amdgcn_mfma_f32_16x16x32_bf16(qf0, kf0, a, 0, 0, 0);
      s16x8 kf1 = *(const s16x8*)&Kl[(j16 * 16 + lr) * LDP + 32 + lh * 8];
      a = __builtin_amdgcn_mfma_f32_16x16x32_bf16(qf1, kf1, a, 0, 0, 0);
      acc[j16] = a;
    }
#pragma unroll
    for (int j16 = 0; j16 < 4; ++j16) {
#pragma unroll
      for (int r = 0; r < 4; ++r) {
        float s = acc[j16][r] * 0.125f;
        if (j16 == 0 && lr == 0) s = -INFINITY;
        int irow = w * 16 + lh * 4 + r;
        float p = __expf(s - m_run[r]) * invl[r];
        attnp[(size_t)(row0 + irow) * S_LEN + kt * BN + j16 * 16 + lr] = p;
        Pp[irow * LDP + j16 * 16 + lr] = f2b(p);
      }
    }
    __syncthreads();
#pragma unroll
    for (int ks = 0; ks < 2; ++ks) {
      s16x8 pf = *(const s16x8*)&Pp[(w * 16 + lr) * LDP + ks * 32 + lh * 8];
#pragma unroll
      for (int d16 = 0; d16 < 4; ++d16) {
        s16x8 vf = *(const s16x8*)&Vt[(d16 * 16 + lr) * LDP + ks * 32 + lh * 8];
        oacc[d16] = __builtin_amdgcn_mfma_f32_16x16x32_bf16(pf, vf, oacc[d16], 0, 0, 0);
      }
    }
  }
#pragma unroll
  for (int d16 = 0; d16 < 4; ++d16) {
#pragma unroll
    for (int r = 0; r < 4; ++r) {
      int irow = w * 16 + lh * 4 + r;
      outp[(size_t)(row0 + irow) * D_DIM + d16 * 16 + lr] = oacc[d16][r];
    }
  }
}

__global__ __launch_bounds__(256) void mask_kernel(float* __restrict__ M) {
  int idx = blockIdx.x * 256 + threadIdx.x;
  int i  = idx >> 9;
  int c4 = (idx & 511) << 2;
  int iblk = i >> 6;
  int jblk = c4 >> 6;
  bool same = (jblk == iblk);
  f32x4 v;
  v[0] = (same || ((c4 & 63) == 0)) ? 1.f : 0.f;
  v[1] = same ? 1.f : 0.f;
  v[2] = same ? 1.f : 0.f;
  v[3] = same ? 1.f : 0.f;
  __builtin_nontemporal_store(v, (f32x4*)(M + (size_t)idx * 4));
}

extern "C" void kernel_launch(void* const* d_in, const int* in_sizes, int n_in,
                              void* d_out, int out_size, void* d_ws, size_t ws_size,
                              hipStream_t stream) {
  const float* Q = (const float*)d_in[0];
  const float* K = (const float*)d_in[1];
  const float* V = (const float*)d_in[2];
  float* out  = (float*)d_out;
  float* attn = out + (size_t)NBH * S_LEN * D_DIM;
  float* M    = attn + (size_t)NBH * S_LEN * S_LEN;

  const size_t elems = (size_t)NBH * S_LEN * D_DIM;      // 4,194,304
  const size_t need  = elems * 2 * 2;                    // Kb + Vtb bf16

  if (ws_size >= need) {
    unsigned short* Kb  = (unsigned short*)d_ws;
    unsigned short* Vtb = Kb + elems;
    prep_kernel<<<dim3(S_LEN / 64, NBH), 256, 0, stream>>>(K, V, Kb, Vtb);
    bsattn_fast<<<NBH * NRT, 512, 0, stream>>>(Q, Kb, Vtb, out, attn, M);
  } else {
    dim3 grid(S_LEN / 64, NBH);
    bsattn_kernel<<<grid, 256, 0, stream>>>(Q, K, V, out, attn);
    mask_kernel<<<(S_LEN * S_LEN / 4) / 256, 256, 0, stream>>>(M);
  }
}

// Round 9
// 158.402 us; speedup vs baseline: 1.4149x; 1.4149x over previous
//
#include <hip/hip_runtime.h>
#include <hip/hip_bf16.h>
#include <cmath>

#define S_LEN 2048
#define D_DIM 64
#define BM 128           // rows per block (two 64-row mask blocks)
#define BN 64            // K-tile cols (== mask BLOCK_SIZE)
#define NKT 32
#define NBH 32
#define NRT (S_LEN / BM) // 16 row-tiles per head
#define LDPF 68          // fp32 P row stride
#define LDP 72           // fallback kernel stride

typedef float f32x4 __attribute__((ext_vector_type(4)));
typedef short s16x8 __attribute__((ext_vector_type(8)));
typedef unsigned int u32x4 __attribute__((ext_vector_type(4)));

union PFU { u32x4 u; s16x8 s; };

__device__ __forceinline__ unsigned short f2b(float x) {
  union { float f; unsigned int u; } un; un.f = x;
  unsigned int u = un.u;
  unsigned int r = (u + 0x7FFF + ((u >> 16) & 1)) >> 16;  // RNE
  return (unsigned short)r;
}

__device__ __forceinline__ unsigned int fbits(float x) {
  union { float f; unsigned int u; } un; un.f = x; return un.u;
}

// pack two fp32 -> (bf16(lo) | bf16(hi)<<16), truncating, one v_perm_b32
__device__ __forceinline__ unsigned int pk2(float lo, float hi) {
  return __builtin_amdgcn_perm(fbits(hi), fbits(lo), 0x07060302u);
}

__device__ __forceinline__ s16x8 pack8(float4 a, float4 b) {
  s16x8 r;
  r[0] = (short)f2b(a.x); r[1] = (short)f2b(a.y);
  r[2] = (short)f2b(a.z); r[3] = (short)f2b(a.w);
  r[4] = (short)f2b(b.x); r[5] = (short)f2b(b.y);
  r[6] = (short)f2b(b.z); r[7] = (short)f2b(b.w);
  return r;
}

// async global->LDS, 16B per lane (dest linear: wave-uniform base + lane*16)
typedef __attribute__((address_space(1))) const unsigned int GU32;
typedef __attribute__((address_space(3))) unsigned int LU32;
__device__ __forceinline__ void gload16(const void* g, void* l) {
  __builtin_amdgcn_global_load_lds((GU32*)g, (LU32*)l, 16, 0, 0);
}

// ---- prep: K fp32->bf16 pack + V fp32->bf16 transpose, one kernel ----
__global__ __launch_bounds__(256) void prep_kernel(
    const float* __restrict__ K, const float* __restrict__ V,
    unsigned short* __restrict__ Kb, unsigned short* __restrict__ Vt) {
  __shared__ unsigned short L[64 * 72];
  const int tid = threadIdx.x;
  const int bh = blockIdx.y;
  const int s0 = blockIdx.x * 64;

  const float* Kp = K + ((size_t)bh * S_LEN + s0) * D_DIM;
  unsigned short* Ko = Kb + ((size_t)bh * S_LEN + s0) * D_DIM;
#pragma unroll
  for (int it = 0; it < 2; ++it) {
    int off = tid * 8 + it * 2048;
    float4 a = *(const float4*)(Kp + off);
    float4 b = *(const float4*)(Kp + off + 4);
    *(s16x8*)(Ko + off) = pack8(a, b);
  }

  const float* Vp = V + ((size_t)bh * S_LEN + s0) * D_DIM;
  for (int it = 0; it < 4; ++it) {
    int lin = it * 256 + tid;
    int r = lin >> 4;
    int c = (lin & 15) << 2;
    float4 v = *(const float4*)(Vp + (size_t)r * D_DIM + c);
    L[(c + 0) * 72 + r] = f2b(v.x);
    L[(c + 1) * 72 + r] = f2b(v.y);
    L[(c + 2) * 72 + r] = f2b(v.z);
    L[(c + 3) * 72 + r] = f2b(v.w);
  }
  __syncthreads();
  unsigned short* Vo = Vt + (size_t)bh * D_DIM * S_LEN + s0;
  for (int it = 0; it < 2; ++it) {
    int lin = it * 256 + tid;
    int d = lin >> 3;
    int c8 = (lin & 7) * 8;
    s16x8 v = *(const s16x8*)&L[d * 72 + c8];
    *(s16x8*)(Vo + (size_t)d * S_LEN + c8) = v;
  }
}

// ---- main fused kernel: R6 pass-2 structure + pass-1 ring + M fold ----
__global__ __launch_bounds__(512, 4) void bsattn_fast(
    const float* __restrict__ Qg_, const unsigned short* __restrict__ Kb,
    const unsigned short* __restrict__ Vtb, float* __restrict__ outg,
    float* __restrict__ attng, float* __restrict__ Mg) {
  // Stage: pass 1 = 4-deep K ring; pass 2 = K dbuf in [0,1], V dbuf in [2,3].
  // Linear [64 rows][64 bf16], source-pre-swizzled 16B cols: (row, c^(row&7)).
  __shared__ __align__(16) unsigned short Stage[4][64 * 64];   // 32 KB
  __shared__ __align__(16) float Pl[BM * LDPF];                // 34.8 KB

  const int tid = threadIdx.x;
  const int w  = tid >> 6;      // 0..7
  const int l  = tid & 63;
  const int lr = l & 15;
  const int lh = l >> 4;

  // XCD swizzle: all 16 row-tiles of a head on one XCD
  const int lin = blockIdx.x;
  const int xcd = lin & 7;
  const int ix  = lin >> 3;
  const int bh  = xcd + 8 * (ix >> 4);
  const int rt  = ix & 15;
  const int row0 = rt * BM;
  const int mb  = rt * 2 + (w >> 2);   // this wave's own (masked) mask-block

  const unsigned short* Kh = Kb  + (size_t)bh * S_LEN * D_DIM;
  const unsigned short* Vh = Vtb + (size_t)bh * D_DIM * S_LEN;
  float* outp  = outg  + (size_t)bh * S_LEN * D_DIM;
  float* attnp = attng + (size_t)bh * S_LEN * S_LEN;

  const float* Qrow = Qg_ + ((size_t)bh * S_LEN + row0 + w * 16 + lr) * D_DIM;
  const s16x8 qf0 = pack8(*(const float4*)(Qrow + lh * 8),
                          *(const float4*)(Qrow + lh * 8 + 4));
  const s16x8 qf1 = pack8(*(const float4*)(Qrow + 32 + lh * 8),
                          *(const float4*)(Qrow + 32 + lh * 8 + 4));

  const float C = 0.18033688011112042f;  // log2(e)/8

  auto STAGE_K = [&](int kt, int b) {
    int row = tid >> 3;
    int c = (tid & 7) ^ (row & 7);
    gload16(Kh + (size_t)kt * 4096 + row * 64 + c * 8, &Stage[b][tid * 8]);
  };
  auto STAGE_V = [&](int kt, int b) {
    int row = tid >> 3;
    int c = (tid & 7) ^ (row & 7);
    gload16(Vh + (size_t)row * S_LEN + kt * 64 + c * 8, &Stage[b][tid * 8]);
  };

  // QK^T (unswapped): acc[j16] rows = w*16+lh*4+r (q), cols = j16*16+lr (k)
  auto QKACC = [&](int b, f32x4* acc) {
#pragma unroll
    for (int j16 = 0; j16 < 4; ++j16) {
      const int j = j16 * 16 + lr;
      const int sw = (j & 7) * 8;
      const s16x8 kf0 = *(const s16x8*)&Stage[b][j * 64 + ((lh * 8) ^ sw)];
      const s16x8 kf1 = *(const s16x8*)&Stage[b][j * 64 + ((32 + lh * 8) ^ sw)];
      f32x4 a = {0.f, 0.f, 0.f, 0.f};
      a = __builtin_amdgcn_mfma_f32_16x16x32_bf16(qf0, kf0, a, 0, 0, 0);
      a = __builtin_amdgcn_mfma_f32_16x16x32_bf16(qf1, kf1, a, 0, 0, 0);
      acc[j16] = a;
    }
  };

  // coalesced nt attn store of tile kt from Pl (quarter-wave = 256B run)
  auto ATTN_STORE = [&](int kt) {
#pragma unroll
    for (int it = 0; it < 4; ++it) {
      const int arow = w * 16 + it * 4 + lh;
      const f32x4 v = *(const f32x4*)&Pl[arow * LDPF + lr * 4];
      __builtin_nontemporal_store(
          v, (f32x4*)(attnp + (size_t)(row0 + arow) * S_LEN + kt * BN + lr * 4));
    }
  };

  // ======== pass 1: denominators, 4-deep counted-vmcnt K ring ========
  float l_run[4] = {0.f, 0.f, 0.f, 0.f};
  STAGE_K(0, 0); STAGE_K(1, 1); STAGE_K(2, 2);
  asm volatile("s_waitcnt vmcnt(2)" ::: "memory");   // tile 0 ready
  __builtin_amdgcn_s_barrier();
  __builtin_amdgcn_sched_barrier(0);

  for (int kt = 0; kt < NKT; ++kt) {
    // wraps (kt=29,30,31) stage tiles 0,1,2 into bufs 0,1,2 for pass 2
    STAGE_K((kt + 3) & 31, (kt + 3) & 3);
    f32x4 acc[4];
    QKACC(kt & 3, acc);
    const float ts = (kt == mb) ? 0.f : 1.f;
#pragma unroll
    for (int r = 0; r < 4; ++r) {
      float e0 = __builtin_amdgcn_exp2f(acc[0][r] * C);
      if (lr == 0) e0 = 0.f;  // block-head column j%64==0
      float e1 = __builtin_amdgcn_exp2f(acc[1][r] * C);
      float e2 = __builtin_amdgcn_exp2f(acc[2][r] * C);
      float e3 = __builtin_amdgcn_exp2f(acc[3][r] * C);
      l_run[r] += ts * (e0 + e1 + e2 + e3);
    }
    __builtin_amdgcn_sched_barrier(0);
    asm volatile("s_waitcnt vmcnt(2)" ::: "memory");  // next tile ready
    __builtin_amdgcn_s_barrier();
    __builtin_amdgcn_sched_barrier(0);
  }

  // settle wrap loads so the V0 overwrite of buf2 can't race K2's landing
  asm volatile("s_waitcnt vmcnt(0)" ::: "memory");

#pragma unroll
  for (int off = 8; off >= 1; off >>= 1)
#pragma unroll
    for (int r = 0; r < 4; ++r) l_run[r] += __shfl_xor(l_run[r], off);
  float invl[4];
#pragma unroll
  for (int r = 0; r < 4; ++r) invl[r] = 1.0f / l_run[r];

  // M mask output folded here (write pipe otherwise idle): 4 rows/block
  {
    const int i0 = blockIdx.x * 4;
#pragma unroll
    for (int rr = 0; rr < 4; ++rr) {
      const int i = i0 + rr;
      const int iblk = i >> 6;
      const int c0 = tid * 4;
      f32x4 v;
#pragma unroll
      for (int c = 0; c < 4; ++c) {
        const int j = c0 + c;
        v[c] = ((j >> 6) == iblk) || ((j & 63) == 0) ? 1.f : 0.f;
      }
      __builtin_nontemporal_store(v, (f32x4*)(Mg + (size_t)i * S_LEN + c0));
    }
  }

  // pass-2 prologue: K0,K1 already in bufs 0,1 (wraps); V0 into buf 2
  STAGE_V(0, 2);
  __syncthreads();   // drains V0 + M stores; all waves synced

  // ======== pass 2 (R6-proven): QK -> P(LDS fp32) -> PV; store deferred ====
  f32x4 oacc[4];
#pragma unroll
  for (int d16 = 0; d16 < 4; ++d16) oacc[d16] = (f32x4){0.f, 0.f, 0.f, 0.f};

  for (int kt = 0; kt < NKT; ++kt) {
    const int kb = kt & 1;
    const int vb = 2 + (kt & 1);
    // VMEM issue order: [2 stage loads] then [4 nt stores of kt-1]
    if (kt < NKT - 1) { STAGE_K(kt + 1, (kt + 1) & 1); STAGE_V(kt + 1, 2 + ((kt + 1) & 1)); }
    if (kt > 0) ATTN_STORE(kt - 1);

    f32x4 acc[4];
    QKACC(kb, acc);
    const float ts = (kt == mb) ? 0.f : 1.f;
#pragma unroll
    for (int j16 = 0; j16 < 4; ++j16)
#pragma unroll
      for (int r = 0; r < 4; ++r) {
        float e = __builtin_amdgcn_exp2f(acc[j16][r] * C) * ts * invl[r];
        if (j16 == 0 && lr == 0) e = 0.f;
        Pl[(w * 16 + lh * 4 + r) * LDPF + j16 * 16 + lr] = e;
      }

#pragma unroll
    for (int ks = 0; ks < 2; ++ks) {
      const float* prow = &Pl[(w * 16 + lr) * LDPF + ks * 32 + lh * 8];
      float4 pa = *(const float4*)prow;
      float4 pb = *(const float4*)(prow + 4);
      PFU p;
      p.u = (u32x4){pk2(pa.x, pa.y), pk2(pa.z, pa.w),
                    pk2(pb.x, pb.y), pk2(pb.z, pb.w)};
#pragma unroll
      for (int d16 = 0; d16 < 4; ++d16) {
        const int vr = d16 * 16 + lr;
        const s16x8 vf = *(const s16x8*)
            &Stage[vb][vr * 64 + ((ks * 32 + lh * 8) ^ ((vr & 7) * 8))];
        oacc[d16] = __builtin_amdgcn_mfma_f32_16x16x32_bf16(p.s, vf, oacc[d16], 0, 0, 0);
      }
    }

    // counted vmcnt: retire the 2 stage loads, leave newest nt stores in flight
    __builtin_amdgcn_sched_barrier(0);
    if (kt == 0) {
      asm volatile("s_waitcnt vmcnt(0)" ::: "memory");
    } else {
      asm volatile("s_waitcnt vmcnt(4)" ::: "memory");
    }
    __builtin_amdgcn_s_barrier();
    __builtin_amdgcn_sched_barrier(0);
  }
  ATTN_STORE(NKT - 1);

#pragma unroll
  for (int d16 = 0; d16 < 4; ++d16)
#pragma unroll
    for (int r = 0; r < 4; ++r) {
      int irow = w * 16 + lh * 4 + r;
      __builtin_nontemporal_store(
          oacc[d16][r], outp + (size_t)(row0 + irow) * D_DIM + d16 * 16 + lr);
    }
}

// ---- fallback (self-contained, fp32 inputs) if ws too small ----
__global__ __launch_bounds__(256) void bsattn_kernel(
    const float* __restrict__ Qg_, const float* __restrict__ Kg_,
    const float* __restrict__ Vg_, float* __restrict__ outg,
    float* __restrict__ attng) {
  __shared__ __align__(16) unsigned short Ql[64 * LDP];
  __shared__ __align__(16) unsigned short Kl[64 * LDP];
  __shared__ __align__(16) unsigned short Vt[64 * LDP];
  __shared__ __align__(16) unsigned short Pp[64 * LDP];
  const int tid = threadIdx.x;
  const int w  = tid >> 6;
  const int l  = tid & 63;
  const int lr = l & 15;
  const int lh = l >> 4;
  const int rt = blockIdx.x;
  const int bh = blockIdx.y;
  const int row0 = rt * 64;
  const float* Qg = Qg_ + (size_t)bh * S_LEN * D_DIM;
  const float* Kg = Kg_ + (size_t)bh * S_LEN * D_DIM;
  const float* Vg = Vg_ + (size_t)bh * S_LEN * D_DIM;
  float* outp  = outg  + (size_t)bh * S_LEN * D_DIM;
  float* attnp = attng + (size_t)bh * S_LEN * S_LEN;
  for (int it = 0; it < 4; ++it) {
    int lin2 = it * 256 + tid;
    int r = lin2 >> 4;
    int c = (lin2 & 15) << 2;
    const float4 v = *(const float4*)(Qg + (size_t)(row0 + r) * D_DIM + c);
    ushort4 bb; bb.x = f2b(v.x); bb.y = f2b(v.y); bb.z = f2b(v.z); bb.w = f2b(v.w);
    *(ushort4*)&Ql[r * LDP + c] = bb;
  }
  __syncthreads();
  const s16x8 qf0 = *(const s16x8*)&Ql[(w * 16 + lr) * LDP + lh * 8];
  const s16x8 qf1 = *(const s16x8*)&Ql[(w * 16 + lr) * LDP + 32 + lh * 8];
  float m_run[4] = {-1e30f, -1e30f, -1e30f, -1e30f};
  float l_run[4] = {0.f, 0.f, 0.f, 0.f};
  for (int kt = 0; kt < NKT; ++kt) {
    if (kt == rt) continue;
    __syncthreads();
    const float* Kt = Kg + (size_t)kt * BN * D_DIM;
    for (int it = 0; it < 4; ++it) {
      int lin2 = it * 256 + tid;
      int r = lin2 >> 4;
      int c = (lin2 & 15) << 2;
      const float4 v = *(const float4*)(Kt + r * D_DIM + c);
      ushort4 bb; bb.x = f2b(v.x); bb.y = f2b(v.y); bb.z = f2b(v.z); bb.w = f2b(v.w);
      *(ushort4*)&Kl[r * LDP + c] = bb;
    }
    __syncthreads();
    f32x4 acc[4];
#pragma unroll
    for (int j16 = 0; j16 < 4; ++j16) {
      f32x4 a = {0.f, 0.f, 0.f, 0.f};
      s16x8 kf0 = *(const s16x8*)&Kl[(j16 * 16 + lr) * LDP + lh * 8];
      a = __builtin_amdgcn_mfma_f32_16x16x32_bf16(qf0, kf0, a, 0, 0, 0);
      s16x8 kf1 = *(const s16x8*)&Kl[(j16 * 16 + lr) * LDP + 32 + lh * 8];
      a = __builtin_amdgcn_mfma_f32_16x16x32_bf16(qf1, kf1, a, 0, 0, 0);
      acc[j16] = a;
    }
#pragma unroll
    for (int r = 0; r < 4; ++r) {
      float s0 = acc[0][r] * 0.125f;
      if (lr == 0) s0 = -INFINITY;
      float s1 = acc[1][r] * 0.125f;
      float s2 = acc[2][r] * 0.125f;
      float s3 = acc[3][r] * 0.125f;
      float tm = fmaxf(fmaxf(s0, s1), fmaxf(s2, s3));
      float mn = fmaxf(m_run[r], tm);
      float scx = __expf(m_run[r] - mn);
      l_run[r] = l_run[r] * scx + __expf(s0 - mn) + __expf(s1 - mn) +
                 __expf(s2 - mn) + __expf(s3 - mn);
      m_run[r] = mn;
    }
  }
#pragma unroll
  for (int off = 8; off >= 1; off >>= 1) {
#pragma unroll
    for (int r = 0; r < 4; ++r) {
      float mo = __shfl_xor(m_run[r], off);
      float lo = __shfl_xor(l_run[r], off);
      float mn = fmaxf(m_run[r], mo);
      l_run[r] = l_run[r] * __expf(m_run[r] - mn) + lo * __expf(mo - mn);
      m_run[r] = mn;
    }
  }
  float invl[4];
#pragma unroll
  for (int r = 0; r < 4; ++r) invl[r] = 1.0f / l_run[r];
  f32x4 oacc[4];
#pragma unroll
  for (int d16 = 0; d16 < 4; ++d16) oacc[d16] = (f32x4){0.f, 0.f, 0.f, 0.f};
  for (int kt = 0; kt < NKT; ++kt) {
    if (kt == rt) {
      for (int it = 0; it < 4; ++it) {
        int lin2 = it * 256 + tid;
        int r = lin2 >> 4;
        int c = (lin2 & 15) << 2;
        float4 z = {0.f, 0.f, 0.f, 0.f};
        *(float4*)(attnp + (size_t)(row0 + r) * S_LEN + kt * BN + c) = z;
      }
      continue;
    }
    __syncthreads();
    const float* Kt  = Kg + (size_t)kt * BN * D_DIM;
    const float* Vtg = Vg + (size_t)kt * BN * D_DIM;
    for (int it = 0; it < 4; ++it) {
      int lin2 = it * 256 + tid;
      int r = lin2 >> 4;
      int c = (lin2 & 15) << 2;
      const float4 v = *(const float4*)(Kt + r * D_DIM + c);
      ushort4 bb; bb.x = f2b(v.x); bb.y = f2b(v.y); bb.z = f2b(v.z); bb.w = f2b(v.w);
      *(ushort4*)&Kl[r * LDP + c] = bb;
      const float4 vv = *(const float4*)(Vtg + r * D_DIM + c);
      Vt[(c + 0) * LDP + r] = f2b(vv.x);
      Vt[(c + 1) * LDP + r] = f2b(vv.y);
      Vt[(c + 2) * LDP + r] = f2b(vv.z);
      Vt[(c + 3) * LDP + r] = f2b(vv.w);
    }
    __syncthreads();
    f32x4 acc[4];
#pragma unroll
    for (int j16 = 0; j16 < 4; ++j16) {
      f32x4 a = {0.f, 0.f, 0.f, 0.f};
      s16x8 kf0 = *(const s16x8*)&Kl[(j16 * 16 + lr) * LDP + lh * 8];
      a = __builtin_amdgcn_mfma_f32_16x16x32_bf16(qf0, kf0, a, 0, 0, 0);
      s16x8 kf1 = *(const s16x8*)&Kl[(j16 * 16 + lr) * LDP + 32 + lh * 8];
      a = __builtin_amdgcn_mfma_f32_16x16x32_bf16(qf1, kf1, a, 0, 0, 0);
      acc[j16] = a;
    }
#pragma unroll
    for (int j16 = 0; j16 < 4; ++j16) {
#pragma unroll
      for (int r = 0; r < 4; ++r) {
        float s = acc[j16][r] * 0.125f;
        if (j16 == 0 && lr == 0) s = -INFINITY;
        int irow = w * 16 + lh * 4 + r;
        float p = __expf(s - m_run[r]) * invl[r];
        attnp[(size_t)(row0 + irow) * S_LEN + kt * BN + j16 * 16 + lr] = p;
        Pp[irow * LDP + j16 * 16 + lr] = f2b(p);
      }
    }
    __syncthreads();
#pragma unroll
    for (int ks = 0; ks < 2; ++ks) {
      s16x8 pf = *(const s16x8*)&Pp[(w * 16 + lr) * LDP + ks * 32 + lh * 8];
#pragma unroll
      for (int d16 = 0; d16 < 4; ++d16) {
        s16x8 vf = *(const s16x8*)&Vt[(d16 * 16 + lr) * LDP + ks * 32 + lh * 8];
        oacc[d16] = __builtin_amdgcn_mfma_f32_16x16x32_bf16(pf, vf, oacc[d16], 0, 0, 0);
      }
    }
  }
#pragma unroll
  for (int d16 = 0; d16 < 4; ++d16) {
#pragma unroll
    for (int r = 0; r < 4; ++r) {
      int irow = w * 16 + lh * 4 + r;
      outp[(size_t)(row0 + irow) * D_DIM + d16 * 16 + lr] = oacc[d16][r];
    }
  }
}

__global__ __launch_bounds__(256) void mask_kernel(float* __restrict__ M) {
  int idx = blockIdx.x * 256 + threadIdx.x;
  int i  = idx >> 9;
  int c4 = (idx & 511) << 2;
  int iblk = i >> 6;
  int jblk = c4 >> 6;
  bool same = (jblk == iblk);
  f32x4 v;
  v[0] = (same || ((c4 & 63) == 0)) ? 1.f : 0.f;
  v[1] = same ? 1.f : 0.f;
  v[2] = same ? 1.f : 0.f;
  v[3] = same ? 1.f : 0.f;
  __builtin_nontemporal_store(v, (f32x4*)(M + (size_t)idx * 4));
}

extern "C" void kernel_launch(void* const* d_in, const int* in_sizes, int n_in,
                              void* d_out, int out_size, void* d_ws, size_t ws_size,
                              hipStream_t stream) {
  const float* Q = (const float*)d_in[0];
  const float* K = (const float*)d_in[1];
  const float* V = (const float*)d_in[2];
  float* out  = (float*)d_out;
  float* attn = out + (size_t)NBH * S_LEN * D_DIM;
  float* M    = attn + (size_t)NBH * S_LEN * S_LEN;

  const size_t elems = (size_t)NBH * S_LEN * D_DIM;      // 4,194,304
  const size_t need  = elems * 2 * 2;                    // Kb + Vtb bf16

  if (ws_size >= need) {
    unsigned short* Kb  = (unsigned short*)d_ws;
    unsigned short* Vtb = Kb + elems;
    prep_kernel<<<dim3(S_LEN / 64, NBH), 256, 0, stream>>>(K, V, Kb, Vtb);
    bsattn_fast<<<NBH * NRT, 512, 0, stream>>>(Q, Kb, Vtb, out, attn, M);
  } else {
    dim3 grid(S_LEN / 64, NBH);
    bsattn_kernel<<<grid, 256, 0, stream>>>(Q, K, V, out, attn);
    mask_kernel<<<(S_LEN * S_LEN / 4) / 256, 256, 0, stream>>>(M);
  }
}